// Round 13
// baseline (340.173 us; speedup 1.0000x reference)
//
#include <hip/hip_runtime.h>
#include <math.h>

#define NP     2048
#define NQTOT  8192
#define DIN    256
#define DIM    200
#define HID    128
#define NOUT3  3
#define NBLK   5
#define TQ     32
#define NTHR   256
#define INVVAR 25.0f
#define NKT    (NP / 32)    // 64 K-tiles (MFMA K=32)
#define NDT    16           // old F-frag d-tiles (V1 fallback)
#define NDT2   14           // FW0 d-tiles (224 cols, 200 real + 24 zero)
#define LATK   224
#define WSCALE 32768.0f
#define NFRAG  656          // MLP frags (fc0 fused away)

using f16x8 = __attribute__((ext_vector_type(8))) _Float16;
using f32x4 = __attribute__((ext_vector_type(4))) float;

// ---- split helpers ----
__device__ __forceinline__ unsigned int pkrtz_u32(float a, float b) {
  auto p = __builtin_amdgcn_cvt_pkrtz(a, b);
  return __builtin_bit_cast(unsigned int, p);
}
__device__ __forceinline__ void pack_f16_2(const float* f, f16x8& h, f16x8& l) {
#pragma unroll
  for (int j = 0; j < 8; ++j) {
    const float v = f[j];
    const _Float16 hh = (_Float16)v;
    h[j] = hh; l[j] = (_Float16)(v - (float)hh);
  }
}
__device__ __forceinline__ void pack_w16(const float* f, f16x8& h, f16x8& l) {
#pragma unroll
  for (int j = 0; j < 8; ++j) {
    const float v = f[j] * WSCALE;
    const _Float16 hh = (_Float16)v;
    h[j] = hh; l[j] = (_Float16)(v - (float)hh);
  }
}
__device__ __forceinline__ void pack_a(const float* f, f16x8& h, f16x8& l) {
  union { f16x8 v; unsigned int u[4]; } H, L;
#pragma unroll
  for (int jp = 0; jp < 4; ++jp) {
    const float a = f[2 * jp], b = f[2 * jp + 1];
    auto hp = __builtin_amdgcn_cvt_pkrtz(a, b);
    H.u[jp] = __builtin_bit_cast(unsigned int, hp);
    L.u[jp] = pkrtz_u32(a - (float)hp[0], b - (float)hp[1]);
  }
  h = H.v; l = L.v;
}
__device__ __forceinline__ unsigned int split_pack(float x) {
  auto hp = __builtin_amdgcn_cvt_pkrtz(x, x);
  return pkrtz_u32(x, x - (float)hp[0]);
}

__device__ __forceinline__ int qsw(int r, int q) {
  return r * TQ + (q ^ (((r >> 2) & 7) << 2));
}
template<int KPAD>
__device__ __forceinline__ int sidx(int q, int k) {
  return q * KPAD + (((k >> 2) ^ (q & 7)) << 2) + (k & 3);
}
template<int KPAD, bool RELU>
__device__ __forceinline__ void store_split4(unsigned int* dst, int k, int qbase, f32x4 v) {
#pragma unroll
  for (int r = 0; r < 4; ++r) {
    float x = v[r];
    if (RELU) x = fmaxf(x, 0.f);
    dst[sidx<KPAD>(qbase + r, k)] = split_pack(x);
  }
}

// ================= pack kernels =================
// NEW: FW0 = F @ fc0_w  (fp32 GEMM, LDS-tiled), split to h/l MFMA-B frags.
// grid 256 = batch(4) x kt(64); frag layout [(b*64+kt)*14 + dt][lane] f16x8.
struct PFW { float Fc[32][32]; float Wc[32][LATK]; };   // 4 KB + 28.7 KB
__global__ __launch_bounds__(NTHR) void pid_packfw(
    const float* __restrict__ F, const float* __restrict__ W0,
    _Float16* __restrict__ wsHi, _Float16* __restrict__ wsLo) {
  __shared__ PFW s;
  const int t = threadIdx.x;
  const int batch = blockIdx.x >> 6, kt = blockIdx.x & 63;
  const int p = t >> 3, ng = t & 7;
  const int n0 = ng * 28;
  float acc[28];
#pragma unroll
  for (int j = 0; j < 28; ++j) acc[j] = 0.f;

#pragma unroll 1
  for (int kc = 0; kc < 8; ++kc) {
    __syncthreads();
    {  // stage F chunk [32p][32k]
      const int pp = t >> 3, k4 = t & 7;
      *(float4*)&s.Fc[pp][k4 * 4] =
          *(const float4*)&F[((size_t)batch * NP + kt * 32 + pp) * DIN + kc * 32 + k4 * 4];
    }
    {  // stage W0 chunk [32k][224], zero-pad n>=200
#pragma unroll
      for (int c = 0; c < 7; ++c) {
        const int idx = c * 256 + t;
        const int kk = idx / 56, c4 = idx % 56;
        const int n4 = c4 * 4;
        float4 v = make_float4(0.f, 0.f, 0.f, 0.f);
        if (n4 < DIM)
          v = *(const float4*)&W0[(size_t)(kc * 32 + kk) * DIM + n4];
        *(float4*)&s.Wc[kk][n4] = v;
      }
    }
    __syncthreads();
#pragma unroll 4
    for (int k = 0; k < 32; ++k) {
      const float fv = s.Fc[p][k];
#pragma unroll
      for (int c = 0; c < 7; ++c) {
        const float4 w = *(const float4*)&s.Wc[k][n0 + 4 * c];
        acc[4 * c + 0] = fmaf(fv, w.x, acc[4 * c + 0]);
        acc[4 * c + 1] = fmaf(fv, w.y, acc[4 * c + 1]);
        acc[4 * c + 2] = fmaf(fv, w.z, acc[4 * c + 2]);
        acc[4 * c + 3] = fmaf(fv, w.w, acc[4 * c + 3]);
      }
    }
  }
  // scatter split store: element (p, n) -> frag[(dt)][lane=(p>>3)*16+n%16][j=p&7]
  const int grp = p >> 3, jj = p & 7;
#pragma unroll
  for (int j2 = 0; j2 < 28; ++j2) {
    const int n = n0 + j2, dt = n >> 4, qn = n & 15;
    const size_t base =
        (((size_t)(batch * 64 + kt) * NDT2 + dt) * 64 + grp * 16 + qn) * 8 + jj;
    const float v = acc[j2];
    const _Float16 hh = (_Float16)v;
    wsHi[base] = hh;
    wsLo[base] = (_Float16)(v - (float)hh);
  }
}

// OLD F-splitter (V1 fallback only)
__global__ __launch_bounds__(NTHR) void pid_packf16(const float* __restrict__ F,
                                                    f16x8* __restrict__ wsHi,
                                                    f16x8* __restrict__ wsLo) {
  const int wid = threadIdx.x >> 6, l = threadIdx.x & 63;
  const int tile = blockIdx.x * 4 + wid;
  const int b  = tile >> 10;
  const int kt = (tile >> 4) & 63;
  const int dt = tile & 15;
  const int grp = l >> 4, qn = l & 15;
  const float* src = F + ((size_t)b * NP + kt * 32 + grp * 8) * DIN + dt * 16 + qn;
  float v[8];
#pragma unroll
  for (int j = 0; j < 8; ++j) v[j] = src[(size_t)j * DIN];
  f16x8 h, lo;
  pack_f16_2(v, h, lo);
  const size_t fi = (size_t)tile * 64 + l;
  wsHi[fi] = h; wsLo[fi] = lo;
}

// MLP weights -> fp16 2-way frags. fc1 [0,56) | fcc_i [56+56i) | w0_i [336+32i)
// | w1_i [496+32i). All K<=200 zero-padded.
__global__ __launch_bounds__(NTHR) void pid_packw(
    const float* __restrict__ fc1_w, const float* __restrict__ fcc_w,
    const float* __restrict__ blk_w0, const float* __restrict__ blk_w1,
    f16x8* __restrict__ Wh, f16x8* __restrict__ Wm) {
  const int wid = threadIdx.x >> 6, l = threadIdx.x & 63;
  const int f = blockIdx.x * 4 + wid;
  if (f >= NFRAG) return;
  const float* src; int Kl, Nl, ks, nt;
  if (f < 56)       { int r = f;       src = fc1_w; Kl = 200; Nl = 128; ks = r / 8; nt = r % 8; }
  else if (f < 336) { int r = f - 56;  int i = r / 56; r %= 56;
                      src = fcc_w + (size_t)i * DIM * HID; Kl = 200; Nl = 128; ks = r / 8; nt = r % 8; }
  else if (f < 496) { int r = f - 336; int i = r / 32; r %= 32;
                      src = blk_w0 + (size_t)i * HID * HID; Kl = 128; Nl = 128; ks = r / 8; nt = r % 8; }
  else              { int r = f - 496; int i = r / 32; r %= 32;
                      src = blk_w1 + (size_t)i * HID * HID; Kl = 128; Nl = 128; ks = r / 8; nt = r % 8; }
  const int grp = l >> 4, n = nt * 16 + (l & 15);
  f16x8 h, m;
#pragma unroll
  for (int j = 0; j < 8; ++j) {
    const int k = ks * 32 + grp * 8 + j;
    const float v = (k < Kl && n < Nl) ? src[(size_t)k * Nl + n] : 0.f;
    const _Float16 hh = (_Float16)v;
    h[j] = hh; m[j] = (_Float16)(v - (float)hh);
  }
  const size_t fi = (size_t)f * 64 + l;
  Wh[fi] = h; Wm[fi] = m;
}

// ================= MFMA MLP stage consumer (R10-proven, no setprio) =========
template<int KS, int NT, int MAXNT, int KPADIN, bool RELUA>
__device__ __forceinline__ void mm_stage(
    const unsigned int* __restrict__ Xs,
    const f16x8* __restrict__ Wh, const f16x8* __restrict__ Wm, int fbase,
    f32x4 acc[2][MAXNT], int wid, int l) {
  const int grp = l >> 4, qn = l & 15;
  f16x8 bhA[MAXNT], bmA[MAXNT], bhB[MAXNT], bmB[MAXNT];

#define LOADF(BH, BM, KSV)                                                    \
  _Pragma("unroll") for (int i = 0; i < MAXNT; ++i) {                         \
    const int nt = wid + i * 4;                                               \
    if (nt < NT) {                                                            \
      const size_t fi = (size_t)(fbase + (KSV) * NT + nt) * 64 + l;           \
      BH[i] = Wh[fi]; BM[i] = Wm[fi];                                         \
    }                                                                         \
  }

#define COMPUTE(KSV, BH, BM)                                                  \
  {                                                                           \
    const int u0 = (KSV) * 8 + grp * 2;                                       \
    f16x8 ah[2], al[2];                                                       \
    _Pragma("unroll") for (int qt = 0; qt < 2; ++qt) {                        \
      const int q = qt * 16 + qn;                                             \
      const unsigned int* row = Xs + q * KPADIN;                              \
      const uint4 lo = *(const uint4*)(row + (((u0) ^ (q & 7)) << 2));        \
      const uint4 hi = *(const uint4*)(row + (((u0 + 1) ^ (q & 7)) << 2));    \
      unsigned int p[8] = {lo.x, lo.y, lo.z, lo.w, hi.x, hi.y, hi.z, hi.w};   \
      if (RELUA) {                                                            \
        _Pragma("unroll") for (int j = 0; j < 8; ++j)                         \
          p[j] = (p[j] & 0x8000u) ? 0u : p[j];                                \
      }                                                                       \
      union { f16x8 v; unsigned int u[4]; } H, L;                             \
      _Pragma("unroll") for (int jp = 0; jp < 4; ++jp) {                      \
        H.u[jp] = __builtin_amdgcn_perm(p[2 * jp + 1], p[2 * jp], 0x05040100u);\
        L.u[jp] = __builtin_amdgcn_perm(p[2 * jp + 1], p[2 * jp], 0x07060302u);\
      }                                                                       \
      ah[qt] = H.v; al[qt] = L.v;                                             \
    }                                                                         \
    _Pragma("unroll") for (int qt = 0; qt < 2; ++qt)                          \
    _Pragma("unroll") for (int i = 0; i < MAXNT; ++i)                         \
      if (wid + i * 4 < NT) {                                                 \
        acc[qt][i] = __builtin_amdgcn_mfma_f32_16x16x32_f16(ah[qt], BH[i], acc[qt][i], 0, 0, 0); \
        acc[qt][i] = __builtin_amdgcn_mfma_f32_16x16x32_f16(ah[qt], BM[i], acc[qt][i], 0, 0, 0); \
        acc[qt][i] = __builtin_amdgcn_mfma_f32_16x16x32_f16(al[qt], BH[i], acc[qt][i], 0, 0, 0); \
      }                                                                       \
  }

  LOADF(bhA, bmA, 0)
#pragma unroll 1
  for (int ks = 0; ks + 1 < KS; ks += 2) {
    LOADF(bhB, bmB, ks + 1)
    COMPUTE(ks, bhA, bmA)
    if (ks + 2 < KS) { LOADF(bhA, bmA, ks + 2) }
    COMPUTE(ks + 1, bhB, bmB)
  }
  if (KS & 1) { COMPUTE(KS - 1, bhA, bmA) }
#undef LOADF
#undef COMPUTE
}

// ================= V2 kernel =================
struct SMemV2 {
  union {
    struct { float ax[NP * 3]; float qx[TQ], qy[TQ], qz[TQ]; } a;  // ~25 KB
    unsigned int lats[32 * LATK];     // split lat, rows 200..223 = 0 (28 KB)
  } r1;
  union {
    float4 exch[28 * 64];             // phase-A partial exchange (28 KB)
    struct { unsigned int nets[32 * 128]; unsigned int tmps[32 * 128]; } nt;
    float netf[128 * 32];
  } r2;                               // 32 KB
  float sS[64];
};

__global__ __launch_bounds__(NTHR, 2) void pid_fused_mfma(
    const float* __restrict__ xyz_q, const float* __restrict__ anchors,
    const f16x8* __restrict__ wsFh, const f16x8* __restrict__ wsFl,
    const f16x8* __restrict__ Wh, const f16x8* __restrict__ Wm,
    const float* __restrict__ fc0_b, const float* __restrict__ fc1_b,
    const float* __restrict__ blk_b0, const float* __restrict__ blk_b1,
    const float* __restrict__ fcc_b,
    const float* __restrict__ out_w, const float* __restrict__ out_b,
    float* __restrict__ out) {
  __shared__ SMemV2 sm;
  const int t = threadIdx.x;
  const int bi = blockIdx.x;
  const int batch = bi & 3;            // XCD-pinned batch
  const int q0 = (bi >> 2) * TQ;

  {  // anchors -> LDS
    const float4* src = (const float4*)(anchors + (size_t)batch * NP * 3);
    float4* dst = (float4*)sm.r1.a.ax;
#pragma unroll
    for (int j = 0; j < (NP * 3 / 4) / NTHR; ++j)
      dst[j * NTHR + t] = src[j * NTHR + t];
  }
  if (t < TQ) {
    const float* qp = xyz_q + ((size_t)batch * NQTOT + q0 + t) * 3;
    sm.r1.a.qx[t] = qp[0]; sm.r1.a.qy[t] = qp[1]; sm.r1.a.qz[t] = qp[2];
  }
  __syncthreads();

  // ---- phase A: lat_partial[224] = softmax_u @ FW0 directly (fc0 fused into
  // pack). Wave (kp = kt parity, dh = dt half of 14); each FW0 fragment read
  // once per block. B loads hoisted above w-calc (R10-proven 1-tile depth).
  const int wid = t >> 6, l = t & 63;
  const int kp = wid & 1;
  const int dh = wid >> 1;
  const int grp = l >> 4, qn = l & 15;
  const float q0x = sm.r1.a.qx[qn],      q0y = sm.r1.a.qy[qn],      q0z = sm.r1.a.qz[qn];
  const float q1x = sm.r1.a.qx[16 + qn], q1y = sm.r1.a.qy[16 + qn], q1z = sm.r1.a.qz[16 + qn];
  const float nC1 = -36.067376f;        // -25*log2(e)
  const float nC2 = -7.2134752e-4f;     // -25*2e-5*log2(e)

  const f16x8* pH = wsFh + ((size_t)(batch * 64 + kp) * NDT2 + dh * 7) * 64 + l;
  const f16x8* pL = wsFl + ((size_t)(batch * 64 + kp) * NDT2 + dh * 7) * 64 + l;

  f32x4 acc[2][7];                      // [qt][d2]
#pragma unroll
  for (int a = 0; a < 2; ++a)
#pragma unroll
    for (int j = 0; j < 7; ++j) acc[a][j] = (f32x4){0.f, 0.f, 0.f, 0.f};
  float s0 = 0.f, s1 = 0.f;

#pragma unroll 1
  for (int kt = kp; kt < NKT; kt += 2) {
    f16x8 bh[7], bl[7];
#pragma unroll
    for (int k = 0; k < 7; ++k) { bh[k] = pH[k * 64]; bl[k] = pL[k * 64]; }

    const int pb = kt * 32 + grp * 8;
    float4 av[6];
    {
      const float4* ap = (const float4*)&sm.r1.a.ax[pb * 3];
#pragma unroll
      for (int j = 0; j < 6; ++j) av[j] = ap[j];
    }
    const float* af = (const float*)av;
    float w8[8];
#pragma unroll
    for (int j = 0; j < 8; ++j) {
      const float dx = af[3 * j] - q0x, dy = af[3 * j + 1] - q0y, dz = af[3 * j + 2] - q0z;
      const float D = fmaf(dx, dx, fmaf(dy, dy, dz * dz));
      const float s = __builtin_amdgcn_sqrtf(D);
      const float u = __builtin_amdgcn_exp2f(fmaf(nC2, s, fmaf(nC1, D, 15.0f)));
      w8[j] = u; s0 += u;
    }
    f16x8 ah0, al0;
    pack_a(w8, ah0, al0);
#pragma unroll
    for (int j = 0; j < 8; ++j) {
      const float dx = af[3 * j] - q1x, dy = af[3 * j + 1] - q1y, dz = af[3 * j + 2] - q1z;
      const float D = fmaf(dx, dx, fmaf(dy, dy, dz * dz));
      const float s = __builtin_amdgcn_sqrtf(D);
      const float u = __builtin_amdgcn_exp2f(fmaf(nC2, s, fmaf(nC1, D, 15.0f)));
      w8[j] = u; s1 += u;
    }
    f16x8 ah1, al1;
    pack_a(w8, ah1, al1);

#define MM3(ACC, AH, AL, BH, BL)                                              \
    ACC = __builtin_amdgcn_mfma_f32_16x16x32_f16(AH, BH, ACC, 0, 0, 0);       \
    ACC = __builtin_amdgcn_mfma_f32_16x16x32_f16(AH, BL, ACC, 0, 0, 0);       \
    ACC = __builtin_amdgcn_mfma_f32_16x16x32_f16(AL, BH, ACC, 0, 0, 0);
#pragma unroll
    for (int k = 0; k < 7; ++k) {
      MM3(acc[0][k], ah0, al0, bh[k], bl[k])
      MM3(acc[1][k], ah1, al1, bh[k], bl[k])
    }
#undef MM3
    pH += 2 * NDT2 * 64; pL += 2 * NDT2 * 64;
  }

  // ---- partial softmax sums
  s0 += __shfl_xor(s0, 16); s0 += __shfl_xor(s0, 32);
  s1 += __shfl_xor(s1, 16); s1 += __shfl_xor(s1, 32);
  if (dh == 0 && l < 16) {
    sm.sS[kp * 32 + qn] = s0;
    sm.sS[kp * 32 + 16 + qn] = s1;
  }
  // ---- partial exchange: kp0 writes fp32 partials (r2), barrier,
  //      kp1 combines + normalizes + bias + split-stores lats (r1).
  float4* P = sm.r2.exch;               // [(qt*14 + dt)][grp*16+qn]
  if (kp == 0) {
#pragma unroll
    for (int qt2 = 0; qt2 < 2; ++qt2)
#pragma unroll
      for (int d2 = 0; d2 < 7; ++d2)
        P[(qt2 * 14 + dh * 7 + d2) * 64 + grp * 16 + qn] =
            make_float4(acc[qt2][d2][0], acc[qt2][d2][1],
                        acc[qt2][d2][2], acc[qt2][d2][3]);
  }
  __syncthreads();
  if (kp == 1) {
    float sc0[4], sc1[4];
#pragma unroll
    for (int r = 0; r < 4; ++r) {
      const int j = grp * 4 + r;
      sc0[r] = __builtin_amdgcn_rcpf(sm.sS[j] + sm.sS[32 + j]);        // 2^15 cancels
      sc1[r] = __builtin_amdgcn_rcpf(sm.sS[16 + j] + sm.sS[48 + j]);
    }
#pragma unroll
    for (int d2 = 0; d2 < 7; ++d2) {
      const int k = (dh * 7 + d2) * 16 + qn;
      const float bb = (k < DIM) ? fc0_b[k] : 0.f;
      const float4 p0 = P[(0 * 14 + dh * 7 + d2) * 64 + grp * 16 + qn];
      const float4 p1 = P[(1 * 14 + dh * 7 + d2) * 64 + grp * 16 + qn];
      const f32x4 v0 = {fmaf(acc[0][d2][0] + p0.x, sc0[0], bb),
                        fmaf(acc[0][d2][1] + p0.y, sc0[1], bb),
                        fmaf(acc[0][d2][2] + p0.z, sc0[2], bb),
                        fmaf(acc[0][d2][3] + p0.w, sc0[3], bb)};
      store_split4<LATK, false>(sm.r1.lats, k, grp * 4, v0);
      const f32x4 v1 = {fmaf(acc[1][d2][0] + p1.x, sc1[0], bb),
                        fmaf(acc[1][d2][1] + p1.y, sc1[1], bb),
                        fmaf(acc[1][d2][2] + p1.z, sc1[2], bb),
                        fmaf(acc[1][d2][3] + p1.w, sc1[3], bb)};
      store_split4<LATK, false>(sm.r1.lats, k, 16 + grp * 4, v1);
    }
  }
  __syncthreads();

  // ---- fc1: net = relu(lat) @ fc1_w + b (net stays in registers)
  f32x4 net[2][2];
#pragma unroll
  for (int i = 0; i < 2; ++i) {
    const float b = fc1_b[(wid + i * 4) * 16 + qn];
#pragma unroll
    for (int q2 = 0; q2 < 2; ++q2) net[q2][i] = (f32x4){b, b, b, b};
  }
  mm_stage<7, 8, 2, LATK, true>(sm.r1.lats, Wh, Wm, 0, net, wid, l);

#pragma unroll 1
  for (int ib = 0; ib < NBLK; ++ib) {
#pragma unroll
    for (int i = 0; i < 2; ++i) {
      const float b = fcc_b[ib * HID + (wid + i * 4) * 16 + qn];
#pragma unroll
      for (int q2 = 0; q2 < 2; ++q2) net[q2][i] += (f32x4){b, b, b, b};
    }
    mm_stage<7, 8, 2, LATK, false>(sm.r1.lats, Wh, Wm, 56 + 56 * ib, net, wid, l);
#pragma unroll
    for (int q2 = 0; q2 < 2; ++q2)
#pragma unroll
      for (int i = 0; i < 2; ++i)
        store_split4<128, true>(sm.r2.nt.nets, (wid + i * 4) * 16 + qn,
                                q2 * 16 + grp * 4, net[q2][i]);
    __syncthreads();
    f32x4 a2[2][2];
#pragma unroll
    for (int i = 0; i < 2; ++i) {
      const float b = blk_b0[ib * HID + (wid + i * 4) * 16 + qn];
#pragma unroll
      for (int q2 = 0; q2 < 2; ++q2) a2[q2][i] = (f32x4){b, b, b, b};
    }
    mm_stage<4, 8, 2, 128, false>(sm.r2.nt.nets, Wh, Wm, 336 + 32 * ib, a2, wid, l);
#pragma unroll
    for (int q2 = 0; q2 < 2; ++q2)
#pragma unroll
      for (int i = 0; i < 2; ++i)
        store_split4<128, true>(sm.r2.nt.tmps, (wid + i * 4) * 16 + qn,
                                q2 * 16 + grp * 4, a2[q2][i]);
    __syncthreads();
#pragma unroll
    for (int i = 0; i < 2; ++i) {
      const float b = blk_b1[ib * HID + (wid + i * 4) * 16 + qn];
#pragma unroll
      for (int q2 = 0; q2 < 2; ++q2) net[q2][i] += (f32x4){b, b, b, b};
    }
    mm_stage<4, 8, 2, 128, false>(sm.r2.nt.tmps, Wh, Wm, 496 + 32 * ib, net, wid, l);
    // no barrier: next nets-store conflicts only with THIS iter's w0 reads,
    // already separated by the post-tmps barrier (R10 analysis).
  }
  __syncthreads();   // w1's tmps reads done before netf overwrites r2

  // ---- publish fp32 net, then out-stage
#pragma unroll
  for (int q2 = 0; q2 < 2; ++q2)
#pragma unroll
    for (int i = 0; i < 2; ++i) {
      const int n = (wid + i * 4) * 16 + qn;
      *(float4*)&sm.r2.netf[n * 32 + q2 * 16 + grp * 4] =
          make_float4(net[q2][i][0], net[q2][i][1], net[q2][i][2], net[q2][i][3]);
    }
  __syncthreads();
  if (t < TQ * NOUT3) {
    const int q = t / NOUT3, n = t - q * NOUT3;
    float s = out_b[n];
#pragma unroll 8
    for (int k = 0; k < HID; ++k)
      s = fmaf(fmaxf(sm.r2.netf[k * 32 + q], 0.f), out_w[k * NOUT3 + n], s);
    out[((size_t)batch * NQTOT + q0 + q) * NOUT3 + n] = s;
  }
}

// ================= V1 fallback: MFMA phase A + fp32 vector MLP ==============
template<int K, bool RELUX, bool ACCY>
__device__ __forceinline__ void stage_h128(const float* __restrict__ X,
                                           const float* __restrict__ Wg,
                                           const float* __restrict__ bg,
                                           float* __restrict__ Y, int t) {
  const int qg = t & 7, ng = t >> 3;
  const int n0 = ng * 4, q0 = qg * 4;
  const float4 bv = *(const float4*)&bg[n0];
  const float br[4] = {bv.x, bv.y, bv.z, bv.w};
  float acc[4][4];
#pragma unroll
  for (int j = 0; j < 4; ++j) {
    if (ACCY) {
      const float4 yv = *(const float4*)&Y[qsw(n0 + j, q0)];
      acc[0][j] = yv.x + br[j]; acc[1][j] = yv.y + br[j];
      acc[2][j] = yv.z + br[j]; acc[3][j] = yv.w + br[j];
    } else {
      acc[0][j] = br[j]; acc[1][j] = br[j]; acc[2][j] = br[j]; acc[3][j] = br[j];
    }
  }
#pragma unroll 2
  for (int k0 = 0; k0 < K; k0 += 8) {
    float4 wr[8];
#pragma unroll
    for (int kk = 0; kk < 8; ++kk)
      wr[kk] = *(const float4*)&Wg[(size_t)(k0 + kk) * HID + n0];
#pragma unroll
    for (int kk = 0; kk < 8; ++kk) {
      float4 xv = *(const float4*)&X[qsw(k0 + kk, q0)];
      if (RELUX) {
        xv.x = fmaxf(xv.x, 0.f); xv.y = fmaxf(xv.y, 0.f);
        xv.z = fmaxf(xv.z, 0.f); xv.w = fmaxf(xv.w, 0.f);
      }
      const float xr[4] = {xv.x, xv.y, xv.z, xv.w};
      const float wl[4] = {wr[kk].x, wr[kk].y, wr[kk].z, wr[kk].w};
#pragma unroll
      for (int i = 0; i < 4; ++i)
#pragma unroll
        for (int j = 0; j < 4; ++j)
          acc[i][j] = fmaf(xr[i], wl[j], acc[i][j]);
    }
  }
#pragma unroll
  for (int j = 0; j < 4; ++j)
    *(float4*)&Y[qsw(n0 + j, q0)] =
        make_float4(acc[0][j], acc[1][j], acc[2][j], acc[3][j]);
}

__device__ __forceinline__ void stage_fc0v(const float* __restrict__ X,
                                           const float* __restrict__ Wg,
                                           const float* __restrict__ bg,
                                           float* __restrict__ Y, int t) {
  const int qg = t & 7, ng = t >> 3;
  const int n0 = ng * 8, q0 = qg * 4;
  const bool act = (ng < 25);
  float acc[4][8];
  if (act) {
    const float4 b0 = *(const float4*)&bg[n0];
    const float4 b1 = *(const float4*)&bg[n0 + 4];
    const float br[8] = {b0.x, b0.y, b0.z, b0.w, b1.x, b1.y, b1.z, b1.w};
#pragma unroll
    for (int j = 0; j < 8; ++j)
#pragma unroll
      for (int i = 0; i < 4; ++i) acc[i][j] = br[j];
  }
#pragma unroll 2
  for (int k0 = 0; k0 < DIN; k0 += 4) {
    if (act) {
      float4 wa[4], wb[4];
#pragma unroll
      for (int kk = 0; kk < 4; ++kk) {
        wa[kk] = *(const float4*)&Wg[(size_t)(k0 + kk) * DIM + n0];
        wb[kk] = *(const float4*)&Wg[(size_t)(k0 + kk) * DIM + n0 + 4];
      }
#pragma unroll
      for (int kk = 0; kk < 4; ++kk) {
        const float4 xv = *(const float4*)&X[qsw(k0 + kk, q0)];
        const float xr[4] = {xv.x, xv.y, xv.z, xv.w};
        const float wl[8] = {wa[kk].x, wa[kk].y, wa[kk].z, wa[kk].w,
                             wb[kk].x, wb[kk].y, wb[kk].z, wb[kk].w};
#pragma unroll
        for (int i = 0; i < 4; ++i)
#pragma unroll
          for (int j = 0; j < 8; ++j)
            acc[i][j] = fmaf(xr[i], wl[j], acc[i][j]);
      }
    }
  }
  if (act) {
#pragma unroll
    for (int j = 0; j < 8; ++j)
      *(float4*)&Y[qsw(n0 + j, q0)] =
          make_float4(acc[0][j], acc[1][j], acc[2][j], acc[3][j]);
  }
}

struct SA1 {
  float ax[NP * 3];
  float qx[TQ], qy[TQ], qz[TQ], m[TQ];
  float sred[8 * TQ];
};
struct SB1 {
  float lat[DIM * TQ];
  union {
    float cT[DIN * TQ];
    struct { float net[HID * TQ]; float tmp[HID * TQ]; } nt;
  } u;
};
struct SMem1 { union { SA1 a; SB1 b; } s; float sS[TQ]; };

__global__ __launch_bounds__(NTHR, 2) void pid_fused_vec(
    const float* __restrict__ xyz_q, const float* __restrict__ anchors,
    const f16x8* __restrict__ wsFh, const f16x8* __restrict__ wsFl,
    const float* __restrict__ fc0_w, const float* __restrict__ fc0_b,
    const float* __restrict__ fc1_w, const float* __restrict__ fc1_b,
    const float* __restrict__ blk_w0, const float* __restrict__ blk_b0,
    const float* __restrict__ blk_w1, const float* __restrict__ blk_b1,
    const float* __restrict__ fcc_w, const float* __restrict__ fcc_b,
    const float* __restrict__ out_w, const float* __restrict__ out_b,
    float* __restrict__ out) {
  __shared__ SMem1 sm;
  const int t = threadIdx.x;
  const int bi = blockIdx.x;
  const int batch = bi & 3;
  const int q0 = (bi >> 2) * TQ;

  {
    const float4* src = (const float4*)(anchors + (size_t)batch * NP * 3);
    float4* dst = (float4*)sm.s.a.ax;
#pragma unroll
    for (int j = 0; j < (NP * 3 / 4) / NTHR; ++j)
      dst[j * NTHR + t] = src[j * NTHR + t];
  }
  if (t < TQ) {
    const float* qp = xyz_q + ((size_t)batch * NQTOT + q0 + t) * 3;
    sm.s.a.qx[t] = qp[0]; sm.s.a.qy[t] = qp[1]; sm.s.a.qz[t] = qp[2];
  }
  __syncthreads();
  {
    const int q = t & 31, g = t >> 5;
    const float qxv = sm.s.a.qx[q], qyv = sm.s.a.qy[q], qzv = sm.s.a.qz[q];
    float mloc = 3.0e38f;
    const float* az = sm.s.a.ax + g * 256 * 3;
    for (int pi = 0; pi < 256; ++pi) {
      const float dx = az[pi * 3 + 0] - qxv;
      const float dy = az[pi * 3 + 1] - qyv;
      const float dz = az[pi * 3 + 2] - qzv;
      mloc = fminf(mloc, fmaf(dx, dx, fmaf(dy, dy, dz * dz)));
    }
    sm.s.a.sred[g * TQ + q] = mloc;
  }
  __syncthreads();
  if (t < TQ) {
    float mv = sm.s.a.sred[t];
#pragma unroll
    for (int g = 1; g < 8; ++g) mv = fminf(mv, sm.s.a.sred[g * TQ + t]);
    const float dmin = sqrtf(mv) + 1e-5f;
    sm.s.a.m[t] = -dmin * dmin * INVVAR;
  }
  __syncthreads();

  const int wid = t >> 6, l = t & 63;
  const int qt = wid & 1;
  const int dgb = (wid >> 1) * 8;
  const int grp = l >> 4, qn = l & 15;
  const float qxv = sm.s.a.qx[qt * 16 + qn];
  const float qyv = sm.s.a.qy[qt * 16 + qn];
  const float qzv = sm.s.a.qz[qt * 16 + qn];
  const float negm = -sm.s.a.m[qt * 16 + qn];
  const f16x8* BH = wsFh + (size_t)batch * NKT * NDT * 64;
  const f16x8* BL = wsFl + (size_t)batch * NKT * NDT * 64;

  f32x4 acc[8];
#pragma unroll
  for (int j = 0; j < 8; ++j) acc[j] = (f32x4){0.f, 0.f, 0.f, 0.f};
  float ssum = 0.f;
#pragma unroll 1
  for (int kt = 0; kt < NKT; ++kt) {
    f16x8 bh[8], bl[8];
#pragma unroll
    for (int d2 = 0; d2 < 8; ++d2) {
      const size_t fi = ((size_t)kt * NDT + dgb + d2) * 64 + l;
      bh[d2] = BH[fi]; bl[d2] = BL[fi];
    }
    const int pb = kt * 32 + grp * 8;
    float4 av[6];
    {
      const float4* ap = (const float4*)&sm.s.a.ax[pb * 3];
#pragma unroll
      for (int j = 0; j < 6; ++j) av[j] = ap[j];
    }
    const float* af = (const float*)av;
    float w8[8];
#pragma unroll
    for (int j = 0; j < 8; ++j) {
      const float dx = af[3 * j] - qxv, dy = af[3 * j + 1] - qyv, dz = af[3 * j + 2] - qzv;
      const float d = sqrtf(fmaf(dx, dx, fmaf(dy, dy, dz * dz))) + 1e-5f;
      const float u = __expf(fmaf(d * d, -INVVAR, negm));
      w8[j] = u; ssum += u;
    }
    f16x8 ah, al;
    pack_w16(w8, ah, al);
#pragma unroll
    for (int d2 = 0; d2 < 8; ++d2)
      acc[d2] = __builtin_amdgcn_mfma_f32_16x16x32_f16(ah, bh[d2], acc[d2], 0, 0, 0);
#pragma unroll
    for (int d2 = 0; d2 < 8; ++d2)
      acc[d2] = __builtin_amdgcn_mfma_f32_16x16x32_f16(ah, bl[d2], acc[d2], 0, 0, 0);
#pragma unroll
    for (int d2 = 0; d2 < 8; ++d2)
      acc[d2] = __builtin_amdgcn_mfma_f32_16x16x32_f16(al, bh[d2], acc[d2], 0, 0, 0);
  }
  ssum += __shfl_xor(ssum, 16);
  ssum += __shfl_xor(ssum, 32);
  if (wid < 2 && grp == 0) sm.sS[qt * 16 + qn] = ssum;
  __syncthreads();
  float sc[4];
#pragma unroll
  for (int r = 0; r < 4; ++r)
    sc[r] = (1.0f / WSCALE) / sm.sS[qt * 16 + grp * 4 + r];
#pragma unroll
  for (int d2 = 0; d2 < 8; ++d2) {
    const int d = (dgb + d2) * 16 + qn;
    *(float4*)&sm.s.b.u.cT[qsw(d, qt * 16 + grp * 4)] =
        make_float4(acc[d2][0] * sc[0], acc[d2][1] * sc[1],
                    acc[d2][2] * sc[2], acc[d2][3] * sc[3]);
  }
  __syncthreads();

  stage_fc0v(sm.s.b.u.cT, fc0_w, fc0_b, sm.s.b.lat, t);
  __syncthreads();
  stage_h128<DIM, true, false>(sm.s.b.lat, fc1_w, fc1_b, sm.s.b.u.nt.net, t);
  __syncthreads();
#pragma unroll 1
  for (int i = 0; i < NBLK; ++i) {
    stage_h128<DIM, false, true>(sm.s.b.lat, fcc_w + (size_t)i * DIM * HID,
                                 fcc_b + i * HID, sm.s.b.u.nt.net, t);
    __syncthreads();
    stage_h128<HID, true, false>(sm.s.b.u.nt.net, blk_w0 + (size_t)i * HID * HID,
                                 blk_b0 + i * HID, sm.s.b.u.nt.tmp, t);
    __syncthreads();
    stage_h128<HID, true, true>(sm.s.b.u.nt.tmp, blk_w1 + (size_t)i * HID * HID,
                                blk_b1 + i * HID, sm.s.b.u.nt.net, t);
    __syncthreads();
  }
  if (t < TQ * NOUT3) {
    const int q = t / NOUT3, n = t - q * NOUT3;
    float s = out_b[n];
    const float* net = sm.s.b.u.nt.net;
#pragma unroll 8
    for (int k = 0; k < HID; ++k)
      s = fmaf(fmaxf(net[k * TQ + (q ^ (((k >> 2) & 7) << 2))], 0.f),
               out_w[k * NOUT3 + n], s);
    out[((size_t)batch * NQTOT + q0 + q) * NOUT3 + n] = s;
  }
}

extern "C" void kernel_launch(void* const* d_in, const int* in_sizes, int n_in,
                              void* d_out, int out_size, void* d_ws, size_t ws_size,
                              hipStream_t stream) {
  (void)in_sizes; (void)n_in; (void)out_size;
  const float* xyz_q        = (const float*)d_in[0];
  const float* anchors      = (const float*)d_in[1];
  const float* anchor_feats = (const float*)d_in[2];
  const float* fc0_w        = (const float*)d_in[3];
  const float* fc0_b        = (const float*)d_in[4];
  const float* fc1_w        = (const float*)d_in[5];
  const float* fc1_b        = (const float*)d_in[6];
  const float* blk_w0       = (const float*)d_in[7];
  const float* blk_b0       = (const float*)d_in[8];
  const float* blk_w1       = (const float*)d_in[9];
  const float* blk_b1       = (const float*)d_in[10];
  const float* fcc_w        = (const float*)d_in[11];
  const float* fcc_b        = (const float*)d_in[12];
  const float* out_w        = (const float*)d_in[13];
  const float* out_b        = (const float*)d_in[14];
  float* out = (float*)d_out;

  // New layout: FW0 frags (2 x 3.5 MiB) + MLP W frags (2 x 656 KiB) = 8.68 MB
  const size_t F2_BYTES = (size_t)4 * 64 * NDT2 * 64 * 16;      // 3,670,016
  const size_t W2_BYTES = (size_t)NFRAG * 64 * 16;              // 671,744
  if (ws_size >= 2 * F2_BYTES + 2 * W2_BYTES) {
    f16x8* wsFh = (f16x8*)d_ws;
    f16x8* wsFl = (f16x8*)((char*)d_ws + F2_BYTES);
    f16x8* Wh   = (f16x8*)((char*)d_ws + 2 * F2_BYTES);
    f16x8* Wm   = (f16x8*)((char*)d_ws + 2 * F2_BYTES + W2_BYTES);
    hipLaunchKernelGGL(pid_packfw, dim3(256), dim3(NTHR), 0, stream,
                       anchor_feats, fc0_w, (_Float16*)wsFh, (_Float16*)wsFl);
    hipLaunchKernelGGL(pid_packw, dim3((NFRAG + 3) / 4), dim3(NTHR), 0, stream,
                       fc1_w, fcc_w, blk_w0, blk_w1, Wh, Wm);
    hipLaunchKernelGGL(pid_fused_mfma, dim3(1024), dim3(NTHR), 0, stream,
                       xyz_q, anchors, wsFh, wsFl, Wh, Wm,
                       fc0_b, fc1_b, blk_b0, blk_b1, fcc_b, out_w, out_b, out);
  } else {
    // V1 fallback: old 16-dt F frags + fp32 vector MLP (needs 8 MiB)
    const size_t F1_BYTES = (size_t)4 * NKT * NDT * 64 * 16;    // 4 MiB
    f16x8* wsFh = (f16x8*)d_ws;
    f16x8* wsFl = (f16x8*)((char*)d_ws + F1_BYTES);
    hipLaunchKernelGGL(pid_packf16, dim3(1024), dim3(NTHR), 0, stream,
                       anchor_feats, wsFh, wsFl);
    hipLaunchKernelGGL(pid_fused_vec, dim3(1024), dim3(NTHR), 0, stream,
                       xyz_q, anchors, wsFh, wsFl,
                       fc0_w, fc0_b, fc1_w, fc1_b, blk_w0, blk_b0,
                       blk_w1, blk_b1, fcc_w, fcc_b, out_w, out_b, out);
  }
}

// Round 14
// 239.617 us; speedup vs baseline: 1.4197x; 1.4197x over previous
//
#include <hip/hip_runtime.h>
#include <math.h>

#define NP     2048
#define NQTOT  8192
#define DIN    256
#define DIM    200
#define HID    128
#define NOUT3  3
#define NBLK   5
#define TQ     32
#define NTHR   256
#define INVVAR 25.0f
#define NKT    (NP / 32)    // 64 K-tiles (MFMA K=32)
#define NDT    16           // old F-frag d-tiles (V1 fallback)
#define NDT2   14           // FW0 d-tiles (224 cols, 200 real + 24 zero)
#define LATK   224
#define WSCALE 32768.0f
#define NFRAG  768          // MLP frags: fc1|fcc|w0|w1|fc0(B-frags for packfw)

using f16x8 = __attribute__((ext_vector_type(8))) _Float16;
using f16x4 = __attribute__((ext_vector_type(4))) _Float16;
using f32x4 = __attribute__((ext_vector_type(4))) float;

// ---- split helpers ----
__device__ __forceinline__ unsigned int pkrtz_u32(float a, float b) {
  auto p = __builtin_amdgcn_cvt_pkrtz(a, b);
  return __builtin_bit_cast(unsigned int, p);
}
__device__ __forceinline__ void pack_f16_2(const float* f, f16x8& h, f16x8& l) {
#pragma unroll
  for (int j = 0; j < 8; ++j) {
    const float v = f[j];
    const _Float16 hh = (_Float16)v;
    h[j] = hh; l[j] = (_Float16)(v - (float)hh);
  }
}
__device__ __forceinline__ void pack_w16(const float* f, f16x8& h, f16x8& l) {
#pragma unroll
  for (int j = 0; j < 8; ++j) {
    const float v = f[j] * WSCALE;
    const _Float16 hh = (_Float16)v;
    h[j] = hh; l[j] = (_Float16)(v - (float)hh);
  }
}
__device__ __forceinline__ void pack_a(const float* f, f16x8& h, f16x8& l) {
  union { f16x8 v; unsigned int u[4]; } H, L;
#pragma unroll
  for (int jp = 0; jp < 4; ++jp) {
    const float a = f[2 * jp], b = f[2 * jp + 1];
    auto hp = __builtin_amdgcn_cvt_pkrtz(a, b);
    H.u[jp] = __builtin_bit_cast(unsigned int, hp);
    L.u[jp] = pkrtz_u32(a - (float)hp[0], b - (float)hp[1]);
  }
  h = H.v; l = L.v;
}
__device__ __forceinline__ unsigned int split_pack(float x) {
  auto hp = __builtin_amdgcn_cvt_pkrtz(x, x);
  return pkrtz_u32(x, x - (float)hp[0]);
}

__device__ __forceinline__ int qsw(int r, int q) {
  return r * TQ + (q ^ (((r >> 2) & 7) << 2));
}
template<int KPAD>
__device__ __forceinline__ int sidx(int q, int k) {
  return q * KPAD + (((k >> 2) ^ (q & 7)) << 2) + (k & 3);
}
template<int KPAD, bool RELU>
__device__ __forceinline__ void store_split4(unsigned int* dst, int k, int qbase, f32x4 v) {
#pragma unroll
  for (int r = 0; r < 4; ++r) {
    float x = v[r];
    if (RELU) x = fmaxf(x, 0.f);
    dst[sidx<KPAD>(qbase + r, k)] = split_pack(x);
  }
}

// ================= pack kernels =================
// MLP weights -> fp16 2-way B-frags. fc1 [0,56) | fcc_i [56+56i) | w0_i
// [336+32i) | w1_i [496+32i) | fc0 [656,768) (K=256, N=224 padded; feeds the
// FW0 MFMA pre-GEMM). All out-of-range k/n zero-padded.
__global__ __launch_bounds__(NTHR) void pid_packw(
    const float* __restrict__ fc0_w, const float* __restrict__ fc1_w,
    const float* __restrict__ fcc_w, const float* __restrict__ blk_w0,
    const float* __restrict__ blk_w1,
    f16x8* __restrict__ Wh, f16x8* __restrict__ Wm) {
  const int wid = threadIdx.x >> 6, l = threadIdx.x & 63;
  const int f = blockIdx.x * 4 + wid;
  if (f >= NFRAG) return;
  const float* src; int Kl, Nl, ks, nt;
  if (f < 56)       { int r = f;       src = fc1_w; Kl = 200; Nl = 128; ks = r / 8; nt = r % 8; }
  else if (f < 336) { int r = f - 56;  int i = r / 56; r %= 56;
                      src = fcc_w + (size_t)i * DIM * HID; Kl = 200; Nl = 128; ks = r / 8; nt = r % 8; }
  else if (f < 496) { int r = f - 336; int i = r / 32; r %= 32;
                      src = blk_w0 + (size_t)i * HID * HID; Kl = 128; Nl = 128; ks = r / 8; nt = r % 8; }
  else if (f < 656) { int r = f - 496; int i = r / 32; r %= 32;
                      src = blk_w1 + (size_t)i * HID * HID; Kl = 128; Nl = 128; ks = r / 8; nt = r % 8; }
  else              { int r = f - 656; src = fc0_w; Kl = 256; Nl = 200; ks = r / 14; nt = r % 14; }
  const int grp = l >> 4, n = nt * 16 + (l & 15);
  f16x8 h, m;
#pragma unroll
  for (int j = 0; j < 8; ++j) {
    const int k = ks * 32 + grp * 8 + j;
    const float v = (k < Kl && n < Nl) ? src[(size_t)k * Nl + n] : 0.f;
    const _Float16 hh = (_Float16)v;
    h[j] = hh; m[j] = (_Float16)(v - (float)hh);
  }
  const size_t fi = (size_t)f * 64 + l;
  Wh[fi] = h; Wm[fi] = m;
}

// FW0 = F @ fc0_w via 3-term fp16 MFMA. A-frags read straight from F (lane qn
// = row, contiguous k -> 2 float4 loads, no LDS); B = fc0 frags from pid_packw.
// Wave = (ptile 16 rows, n-half 7 tiles); D maps so each (thread,ntile) h/l
// store is one aligned 8B f16x4 write.
__global__ __launch_bounds__(NTHR) void pid_packfw(
    const float* __restrict__ F,
    const f16x8* __restrict__ Wh, const f16x8* __restrict__ Wm,
    _Float16* __restrict__ outH, _Float16* __restrict__ outL) {
  const int t = threadIdx.x;
  const int w = t >> 6, l = t & 63;
  const int grp = l >> 4, qn = l & 15;
  const int pt = blockIdx.x * 2 + (w >> 1);   // global ptile 0..511
  const int nh = w & 1;
  const int batch = pt >> 7, ptl = pt & 127;
  const int kt = ptl >> 1;
  const int grp2 = ((ptl & 1) << 1) + (grp >> 1);

  f32x4 acc[7];
#pragma unroll
  for (int j = 0; j < 7; ++j) acc[j] = (f32x4){0.f, 0.f, 0.f, 0.f};

  const float* fa0 = F + ((size_t)batch * NP + ptl * 16 + qn) * DIN + grp * 8;
#pragma unroll 1
  for (int ks = 0; ks < 8; ++ks) {
    float av8[8];
    *(float4*)&av8[0] = *(const float4*)(fa0 + ks * 32);
    *(float4*)&av8[4] = *(const float4*)(fa0 + ks * 32 + 4);
    f16x8 ah, al;
    pack_f16_2(av8, ah, al);
#pragma unroll
    for (int nt2 = 0; nt2 < 7; ++nt2) {
      const size_t fi = (size_t)(656 + ks * 14 + nh * 7 + nt2) * 64 + l;
      const f16x8 bh = Wh[fi], bm = Wm[fi];
      f32x4 a = acc[nt2];
      a = __builtin_amdgcn_mfma_f32_16x16x32_f16(ah, bh, a, 0, 0, 0);
      a = __builtin_amdgcn_mfma_f32_16x16x32_f16(ah, bm, a, 0, 0, 0);
      a = __builtin_amdgcn_mfma_f32_16x16x32_f16(al, bh, a, 0, 0, 0);
      acc[nt2] = a;
    }
  }
#pragma unroll
  for (int nt2 = 0; nt2 < 7; ++nt2) {
    const int nt = nh * 7 + nt2;
    f16x4 hv, lv;
#pragma unroll
    for (int r = 0; r < 4; ++r) {
      const float v = acc[nt2][r];
      const _Float16 hh = (_Float16)v;
      hv[r] = hh; lv[r] = (_Float16)(v - (float)hh);
    }
    const size_t base =
        (((size_t)(batch * 64 + kt) * NDT2 + nt) * 64 + grp2 * 16 + qn) * 8 +
        (grp & 1) * 4;
    *(f16x4*)(outH + base) = hv;
    *(f16x4*)(outL + base) = lv;
  }
}

// OLD F-splitter (V1 fallback only)
__global__ __launch_bounds__(NTHR) void pid_packf16(const float* __restrict__ F,
                                                    f16x8* __restrict__ wsHi,
                                                    f16x8* __restrict__ wsLo) {
  const int wid = threadIdx.x >> 6, l = threadIdx.x & 63;
  const int tile = blockIdx.x * 4 + wid;
  const int b  = tile >> 10;
  const int kt = (tile >> 4) & 63;
  const int dt = tile & 15;
  const int grp = l >> 4, qn = l & 15;
  const float* src = F + ((size_t)b * NP + kt * 32 + grp * 8) * DIN + dt * 16 + qn;
  float v[8];
#pragma unroll
  for (int j = 0; j < 8; ++j) v[j] = src[(size_t)j * DIN];
  f16x8 h, lo;
  pack_f16_2(v, h, lo);
  const size_t fi = (size_t)tile * 64 + l;
  wsHi[fi] = h; wsLo[fi] = lo;
}

// ================= MFMA MLP stage consumer (R10-proven) =================
template<int KS, int NT, int MAXNT, int KPADIN, bool RELUA>
__device__ __forceinline__ void mm_stage(
    const unsigned int* __restrict__ Xs,
    const f16x8* __restrict__ Wh, const f16x8* __restrict__ Wm, int fbase,
    f32x4 acc[2][MAXNT], int wid, int l) {
  const int grp = l >> 4, qn = l & 15;
  f16x8 bhA[MAXNT], bmA[MAXNT], bhB[MAXNT], bmB[MAXNT];

#define LOADF(BH, BM, KSV)                                                    \
  _Pragma("unroll") for (int i = 0; i < MAXNT; ++i) {                         \
    const int nt = wid + i * 4;                                               \
    if (nt < NT) {                                                            \
      const size_t fi = (size_t)(fbase + (KSV) * NT + nt) * 64 + l;           \
      BH[i] = Wh[fi]; BM[i] = Wm[fi];                                         \
    }                                                                         \
  }

#define COMPUTE(KSV, BH, BM)                                                  \
  {                                                                           \
    const int u0 = (KSV) * 8 + grp * 2;                                       \
    f16x8 ah[2], al[2];                                                       \
    _Pragma("unroll") for (int qt = 0; qt < 2; ++qt) {                        \
      const int q = qt * 16 + qn;                                             \
      const unsigned int* row = Xs + q * KPADIN;                              \
      const uint4 lo = *(const uint4*)(row + (((u0) ^ (q & 7)) << 2));        \
      const uint4 hi = *(const uint4*)(row + (((u0 + 1) ^ (q & 7)) << 2));    \
      unsigned int p[8] = {lo.x, lo.y, lo.z, lo.w, hi.x, hi.y, hi.z, hi.w};   \
      if (RELUA) {                                                            \
        _Pragma("unroll") for (int j = 0; j < 8; ++j)                         \
          p[j] = (p[j] & 0x8000u) ? 0u : p[j];                                \
      }                                                                       \
      union { f16x8 v; unsigned int u[4]; } H, L;                             \
      _Pragma("unroll") for (int jp = 0; jp < 4; ++jp) {                      \
        H.u[jp] = __builtin_amdgcn_perm(p[2 * jp + 1], p[2 * jp], 0x05040100u);\
        L.u[jp] = __builtin_amdgcn_perm(p[2 * jp + 1], p[2 * jp], 0x07060302u);\
      }                                                                       \
      ah[qt] = H.v; al[qt] = L.v;                                             \
    }                                                                         \
    _Pragma("unroll") for (int qt = 0; qt < 2; ++qt)                          \
    _Pragma("unroll") for (int i = 0; i < MAXNT; ++i)                         \
      if (wid + i * 4 < NT) {                                                 \
        acc[qt][i] = __builtin_amdgcn_mfma_f32_16x16x32_f16(ah[qt], BH[i], acc[qt][i], 0, 0, 0); \
        acc[qt][i] = __builtin_amdgcn_mfma_f32_16x16x32_f16(ah[qt], BM[i], acc[qt][i], 0, 0, 0); \
        acc[qt][i] = __builtin_amdgcn_mfma_f32_16x16x32_f16(al[qt], BH[i], acc[qt][i], 0, 0, 0); \
      }                                                                       \
  }

  LOADF(bhA, bmA, 0)
#pragma unroll 1
  for (int ks = 0; ks + 1 < KS; ks += 2) {
    LOADF(bhB, bmB, ks + 1)
    COMPUTE(ks, bhA, bmA)
    if (ks + 2 < KS) { LOADF(bhA, bmA, ks + 2) }
    COMPUTE(ks + 1, bhB, bmB)
  }
  if (KS & 1) { COMPUTE(KS - 1, bhA, bmA) }
#undef LOADF
#undef COMPUTE
}

// ================= V2 kernel (identical to R13's proven 224 us) =============
struct SMemV2 {
  union {
    struct { float ax[NP * 3]; float qx[TQ], qy[TQ], qz[TQ]; } a;  // ~25 KB
    unsigned int lats[32 * LATK];     // split lat, rows 200..223 = 0 (28 KB)
  } r1;
  union {
    float4 exch[28 * 64];             // phase-A partial exchange (28 KB)
    struct { unsigned int nets[32 * 128]; unsigned int tmps[32 * 128]; } nt;
    float netf[128 * 32];
  } r2;                               // 32 KB
  float sS[64];
};

__global__ __launch_bounds__(NTHR, 2) void pid_fused_mfma(
    const float* __restrict__ xyz_q, const float* __restrict__ anchors,
    const f16x8* __restrict__ wsFh, const f16x8* __restrict__ wsFl,
    const f16x8* __restrict__ Wh, const f16x8* __restrict__ Wm,
    const float* __restrict__ fc0_b, const float* __restrict__ fc1_b,
    const float* __restrict__ blk_b0, const float* __restrict__ blk_b1,
    const float* __restrict__ fcc_b,
    const float* __restrict__ out_w, const float* __restrict__ out_b,
    float* __restrict__ out) {
  __shared__ SMemV2 sm;
  const int t = threadIdx.x;
  const int bi = blockIdx.x;
  const int batch = bi & 3;            // XCD-pinned batch
  const int q0 = (bi >> 2) * TQ;

  {  // anchors -> LDS
    const float4* src = (const float4*)(anchors + (size_t)batch * NP * 3);
    float4* dst = (float4*)sm.r1.a.ax;
#pragma unroll
    for (int j = 0; j < (NP * 3 / 4) / NTHR; ++j)
      dst[j * NTHR + t] = src[j * NTHR + t];
  }
  if (t < TQ) {
    const float* qp = xyz_q + ((size_t)batch * NQTOT + q0 + t) * 3;
    sm.r1.a.qx[t] = qp[0]; sm.r1.a.qy[t] = qp[1]; sm.r1.a.qz[t] = qp[2];
  }
  __syncthreads();

  const int wid = t >> 6, l = t & 63;
  const int kp = wid & 1;
  const int dh = wid >> 1;
  const int grp = l >> 4, qn = l & 15;
  const float q0x = sm.r1.a.qx[qn],      q0y = sm.r1.a.qy[qn],      q0z = sm.r1.a.qz[qn];
  const float q1x = sm.r1.a.qx[16 + qn], q1y = sm.r1.a.qy[16 + qn], q1z = sm.r1.a.qz[16 + qn];
  const float nC1 = -36.067376f;        // -25*log2(e)
  const float nC2 = -7.2134752e-4f;     // -25*2e-5*log2(e)

  const f16x8* pH = wsFh + ((size_t)(batch * 64 + kp) * NDT2 + dh * 7) * 64 + l;
  const f16x8* pL = wsFl + ((size_t)(batch * 64 + kp) * NDT2 + dh * 7) * 64 + l;

  f32x4 acc[2][7];
#pragma unroll
  for (int a = 0; a < 2; ++a)
#pragma unroll
    for (int j = 0; j < 7; ++j) acc[a][j] = (f32x4){0.f, 0.f, 0.f, 0.f};
  float s0 = 0.f, s1 = 0.f;

#pragma unroll 1
  for (int kt = kp; kt < NKT; kt += 2) {
    f16x8 bh[7], bl[7];
#pragma unroll
    for (int k = 0; k < 7; ++k) { bh[k] = pH[k * 64]; bl[k] = pL[k * 64]; }

    const int pb = kt * 32 + grp * 8;
    float4 av[6];
    {
      const float4* ap = (const float4*)&sm.r1.a.ax[pb * 3];
#pragma unroll
      for (int j = 0; j < 6; ++j) av[j] = ap[j];
    }
    const float* af = (const float*)av;
    float w8[8];
#pragma unroll
    for (int j = 0; j < 8; ++j) {
      const float dx = af[3 * j] - q0x, dy = af[3 * j + 1] - q0y, dz = af[3 * j + 2] - q0z;
      const float D = fmaf(dx, dx, fmaf(dy, dy, dz * dz));
      const float s = __builtin_amdgcn_sqrtf(D);
      const float u = __builtin_amdgcn_exp2f(fmaf(nC2, s, fmaf(nC1, D, 15.0f)));
      w8[j] = u; s0 += u;
    }
    f16x8 ah0, al0;
    pack_a(w8, ah0, al0);
#pragma unroll
    for (int j = 0; j < 8; ++j) {
      const float dx = af[3 * j] - q1x, dy = af[3 * j + 1] - q1y, dz = af[3 * j + 2] - q1z;
      const float D = fmaf(dx, dx, fmaf(dy, dy, dz * dz));
      const float s = __builtin_amdgcn_sqrtf(D);
      const float u = __builtin_amdgcn_exp2f(fmaf(nC2, s, fmaf(nC1, D, 15.0f)));
      w8[j] = u; s1 += u;
    }
    f16x8 ah1, al1;
    pack_a(w8, ah1, al1);

#define MM3(ACC, AH, AL, BH, BL)                                              \
    ACC = __builtin_amdgcn_mfma_f32_16x16x32_f16(AH, BH, ACC, 0, 0, 0);       \
    ACC = __builtin_amdgcn_mfma_f32_16x16x32_f16(AH, BL, ACC, 0, 0, 0);       \
    ACC = __builtin_amdgcn_mfma_f32_16x16x32_f16(AL, BH, ACC, 0, 0, 0);
#pragma unroll
    for (int k = 0; k < 7; ++k) {
      MM3(acc[0][k], ah0, al0, bh[k], bl[k])
      MM3(acc[1][k], ah1, al1, bh[k], bl[k])
    }
#undef MM3
    pH += 2 * NDT2 * 64; pL += 2 * NDT2 * 64;
  }

  s0 += __shfl_xor(s0, 16); s0 += __shfl_xor(s0, 32);
  s1 += __shfl_xor(s1, 16); s1 += __shfl_xor(s1, 32);
  if (dh == 0 && l < 16) {
    sm.sS[kp * 32 + qn] = s0;
    sm.sS[kp * 32 + 16 + qn] = s1;
  }
  float4* P = sm.r2.exch;
  if (kp == 0) {
#pragma unroll
    for (int qt2 = 0; qt2 < 2; ++qt2)
#pragma unroll
      for (int d2 = 0; d2 < 7; ++d2)
        P[(qt2 * 14 + dh * 7 + d2) * 64 + grp * 16 + qn] =
            make_float4(acc[qt2][d2][0], acc[qt2][d2][1],
                        acc[qt2][d2][2], acc[qt2][d2][3]);
  }
  __syncthreads();
  if (kp == 1) {
    float sc0[4], sc1[4];
#pragma unroll
    for (int r = 0; r < 4; ++r) {
      const int j = grp * 4 + r;
      sc0[r] = __builtin_amdgcn_rcpf(sm.sS[j] + sm.sS[32 + j]);
      sc1[r] = __builtin_amdgcn_rcpf(sm.sS[16 + j] + sm.sS[48 + j]);
    }
#pragma unroll
    for (int d2 = 0; d2 < 7; ++d2) {
      const int k = (dh * 7 + d2) * 16 + qn;
      const float bb = (k < DIM) ? fc0_b[k] : 0.f;
      const float4 p0 = P[(0 * 14 + dh * 7 + d2) * 64 + grp * 16 + qn];
      const float4 p1 = P[(1 * 14 + dh * 7 + d2) * 64 + grp * 16 + qn];
      const f32x4 v0 = {fmaf(acc[0][d2][0] + p0.x, sc0[0], bb),
                        fmaf(acc[0][d2][1] + p0.y, sc0[1], bb),
                        fmaf(acc[0][d2][2] + p0.z, sc0[2], bb),
                        fmaf(acc[0][d2][3] + p0.w, sc0[3], bb)};
      store_split4<LATK, false>(sm.r1.lats, k, grp * 4, v0);
      const f32x4 v1 = {fmaf(acc[1][d2][0] + p1.x, sc1[0], bb),
                        fmaf(acc[1][d2][1] + p1.y, sc1[1], bb),
                        fmaf(acc[1][d2][2] + p1.z, sc1[2], bb),
                        fmaf(acc[1][d2][3] + p1.w, sc1[3], bb)};
      store_split4<LATK, false>(sm.r1.lats, k, 16 + grp * 4, v1);
    }
  }
  __syncthreads();

  f32x4 net[2][2];
#pragma unroll
  for (int i = 0; i < 2; ++i) {
    const float b = fc1_b[(wid + i * 4) * 16 + qn];
#pragma unroll
    for (int q2 = 0; q2 < 2; ++q2) net[q2][i] = (f32x4){b, b, b, b};
  }
  mm_stage<7, 8, 2, LATK, true>(sm.r1.lats, Wh, Wm, 0, net, wid, l);

#pragma unroll 1
  for (int ib = 0; ib < NBLK; ++ib) {
#pragma unroll
    for (int i = 0; i < 2; ++i) {
      const float b = fcc_b[ib * HID + (wid + i * 4) * 16 + qn];
#pragma unroll
      for (int q2 = 0; q2 < 2; ++q2) net[q2][i] += (f32x4){b, b, b, b};
    }
    mm_stage<7, 8, 2, LATK, false>(sm.r1.lats, Wh, Wm, 56 + 56 * ib, net, wid, l);
#pragma unroll
    for (int q2 = 0; q2 < 2; ++q2)
#pragma unroll
      for (int i = 0; i < 2; ++i)
        store_split4<128, true>(sm.r2.nt.nets, (wid + i * 4) * 16 + qn,
                                q2 * 16 + grp * 4, net[q2][i]);
    __syncthreads();
    f32x4 a2[2][2];
#pragma unroll
    for (int i = 0; i < 2; ++i) {
      const float b = blk_b0[ib * HID + (wid + i * 4) * 16 + qn];
#pragma unroll
      for (int q2 = 0; q2 < 2; ++q2) a2[q2][i] = (f32x4){b, b, b, b};
    }
    mm_stage<4, 8, 2, 128, false>(sm.r2.nt.nets, Wh, Wm, 336 + 32 * ib, a2, wid, l);
#pragma unroll
    for (int q2 = 0; q2 < 2; ++q2)
#pragma unroll
      for (int i = 0; i < 2; ++i)
        store_split4<128, true>(sm.r2.nt.tmps, (wid + i * 4) * 16 + qn,
                                q2 * 16 + grp * 4, a2[q2][i]);
    __syncthreads();
#pragma unroll
    for (int i = 0; i < 2; ++i) {
      const float b = blk_b1[ib * HID + (wid + i * 4) * 16 + qn];
#pragma unroll
      for (int q2 = 0; q2 < 2; ++q2) net[q2][i] += (f32x4){b, b, b, b};
    }
    mm_stage<4, 8, 2, 128, false>(sm.r2.nt.tmps, Wh, Wm, 496 + 32 * ib, net, wid, l);
  }
  __syncthreads();

#pragma unroll
  for (int q2 = 0; q2 < 2; ++q2)
#pragma unroll
    for (int i = 0; i < 2; ++i) {
      const int n = (wid + i * 4) * 16 + qn;
      *(float4*)&sm.r2.netf[n * 32 + q2 * 16 + grp * 4] =
          make_float4(net[q2][i][0], net[q2][i][1], net[q2][i][2], net[q2][i][3]);
    }
  __syncthreads();
  if (t < TQ * NOUT3) {
    const int q = t / NOUT3, n = t - q * NOUT3;
    float s = out_b[n];
#pragma unroll 8
    for (int k = 0; k < HID; ++k)
      s = fmaf(fmaxf(sm.r2.netf[k * 32 + q], 0.f), out_w[k * NOUT3 + n], s);
    out[((size_t)batch * NQTOT + q0 + q) * NOUT3 + n] = s;
  }
}

// ================= V1 fallback: MFMA phase A + fp32 vector MLP ==============
template<int K, bool RELUX, bool ACCY>
__device__ __forceinline__ void stage_h128(const float* __restrict__ X,
                                           const float* __restrict__ Wg,
                                           const float* __restrict__ bg,
                                           float* __restrict__ Y, int t) {
  const int qg = t & 7, ng = t >> 3;
  const int n0 = ng * 4, q0 = qg * 4;
  const float4 bv = *(const float4*)&bg[n0];
  const float br[4] = {bv.x, bv.y, bv.z, bv.w};
  float acc[4][4];
#pragma unroll
  for (int j = 0; j < 4; ++j) {
    if (ACCY) {
      const float4 yv = *(const float4*)&Y[qsw(n0 + j, q0)];
      acc[0][j] = yv.x + br[j]; acc[1][j] = yv.y + br[j];
      acc[2][j] = yv.z + br[j]; acc[3][j] = yv.w + br[j];
    } else {
      acc[0][j] = br[j]; acc[1][j] = br[j]; acc[2][j] = br[j]; acc[3][j] = br[j];
    }
  }
#pragma unroll 2
  for (int k0 = 0; k0 < K; k0 += 8) {
    float4 wr[8];
#pragma unroll
    for (int kk = 0; kk < 8; ++kk)
      wr[kk] = *(const float4*)&Wg[(size_t)(k0 + kk) * HID + n0];
#pragma unroll
    for (int kk = 0; kk < 8; ++kk) {
      float4 xv = *(const float4*)&X[qsw(k0 + kk, q0)];
      if (RELUX) {
        xv.x = fmaxf(xv.x, 0.f); xv.y = fmaxf(xv.y, 0.f);
        xv.z = fmaxf(xv.z, 0.f); xv.w = fmaxf(xv.w, 0.f);
      }
      const float xr[4] = {xv.x, xv.y, xv.z, xv.w};
      const float wl[4] = {wr[kk].x, wr[kk].y, wr[kk].z, wr[kk].w};
#pragma unroll
      for (int i = 0; i < 4; ++i)
#pragma unroll
        for (int j = 0; j < 4; ++j)
          acc[i][j] = fmaf(xr[i], wl[j], acc[i][j]);
    }
  }
#pragma unroll
  for (int j = 0; j < 4; ++j)
    *(float4*)&Y[qsw(n0 + j, q0)] =
        make_float4(acc[0][j], acc[1][j], acc[2][j], acc[3][j]);
}

__device__ __forceinline__ void stage_fc0v(const float* __restrict__ X,
                                           const float* __restrict__ Wg,
                                           const float* __restrict__ bg,
                                           float* __restrict__ Y, int t) {
  const int qg = t & 7, ng = t >> 3;
  const int n0 = ng * 8, q0 = qg * 4;
  const bool act = (ng < 25);
  float acc[4][8];
  if (act) {
    const float4 b0 = *(const float4*)&bg[n0];
    const float4 b1 = *(const float4*)&bg[n0 + 4];
    const float br[8] = {b0.x, b0.y, b0.z, b0.w, b1.x, b1.y, b1.z, b1.w};
#pragma unroll
    for (int j = 0; j < 8; ++j)
#pragma unroll
      for (int i = 0; i < 4; ++i) acc[i][j] = br[j];
  }
#pragma unroll 2
  for (int k0 = 0; k0 < DIN; k0 += 4) {
    if (act) {
      float4 wa[4], wb[4];
#pragma unroll
      for (int kk = 0; kk < 4; ++kk) {
        wa[kk] = *(const float4*)&Wg[(size_t)(k0 + kk) * DIM + n0];
        wb[kk] = *(const float4*)&Wg[(size_t)(k0 + kk) * DIM + n0 + 4];
      }
#pragma unroll
      for (int kk = 0; kk < 4; ++kk) {
        const float4 xv = *(const float4*)&X[qsw(k0 + kk, q0)];
        const float xr[4] = {xv.x, xv.y, xv.z, xv.w};
        const float wl[8] = {wa[kk].x, wa[kk].y, wa[kk].z, wa[kk].w,
                             wb[kk].x, wb[kk].y, wb[kk].z, wb[kk].w};
#pragma unroll
        for (int i = 0; i < 4; ++i)
#pragma unroll
          for (int j = 0; j < 8; ++j)
            acc[i][j] = fmaf(xr[i], wl[j], acc[i][j]);
      }
    }
  }
  if (act) {
#pragma unroll
    for (int j = 0; j < 8; ++j)
      *(float4*)&Y[qsw(n0 + j, q0)] =
          make_float4(acc[0][j], acc[1][j], acc[2][j], acc[3][j]);
  }
}

struct SA1 {
  float ax[NP * 3];
  float qx[TQ], qy[TQ], qz[TQ], m[TQ];
  float sred[8 * TQ];
};
struct SB1 {
  float lat[DIM * TQ];
  union {
    float cT[DIN * TQ];
    struct { float net[HID * TQ]; float tmp[HID * TQ]; } nt;
  } u;
};
struct SMem1 { union { SA1 a; SB1 b; } s; float sS[TQ]; };

__global__ __launch_bounds__(NTHR, 2) void pid_fused_vec(
    const float* __restrict__ xyz_q, const float* __restrict__ anchors,
    const f16x8* __restrict__ wsFh, const f16x8* __restrict__ wsFl,
    const float* __restrict__ fc0_w, const float* __restrict__ fc0_b,
    const float* __restrict__ fc1_w, const float* __restrict__ fc1_b,
    const float* __restrict__ blk_w0, const float* __restrict__ blk_b0,
    const float* __restrict__ blk_w1, const float* __restrict__ blk_b1,
    const float* __restrict__ fcc_w, const float* __restrict__ fcc_b,
    const float* __restrict__ out_w, const float* __restrict__ out_b,
    float* __restrict__ out) {
  __shared__ SMem1 sm;
  const int t = threadIdx.x;
  const int bi = blockIdx.x;
  const int batch = bi & 3;
  const int q0 = (bi >> 2) * TQ;

  {
    const float4* src = (const float4*)(anchors + (size_t)batch * NP * 3);
    float4* dst = (float4*)sm.s.a.ax;
#pragma unroll
    for (int j = 0; j < (NP * 3 / 4) / NTHR; ++j)
      dst[j * NTHR + t] = src[j * NTHR + t];
  }
  if (t < TQ) {
    const float* qp = xyz_q + ((size_t)batch * NQTOT + q0 + t) * 3;
    sm.s.a.qx[t] = qp[0]; sm.s.a.qy[t] = qp[1]; sm.s.a.qz[t] = qp[2];
  }
  __syncthreads();
  {
    const int q = t & 31, g = t >> 5;
    const float qxv = sm.s.a.qx[q], qyv = sm.s.a.qy[q], qzv = sm.s.a.qz[q];
    float mloc = 3.0e38f;
    const float* az = sm.s.a.ax + g * 256 * 3;
    for (int pi = 0; pi < 256; ++pi) {
      const float dx = az[pi * 3 + 0] - qxv;
      const float dy = az[pi * 3 + 1] - qyv;
      const float dz = az[pi * 3 + 2] - qzv;
      mloc = fminf(mloc, fmaf(dx, dx, fmaf(dy, dy, dz * dz)));
    }
    sm.s.a.sred[g * TQ + q] = mloc;
  }
  __syncthreads();
  if (t < TQ) {
    float mv = sm.s.a.sred[t];
#pragma unroll
    for (int g = 1; g < 8; ++g) mv = fminf(mv, sm.s.a.sred[g * TQ + t]);
    const float dmin = sqrtf(mv) + 1e-5f;
    sm.s.a.m[t] = -dmin * dmin * INVVAR;
  }
  __syncthreads();

  const int wid = t >> 6, l = t & 63;
  const int qt = wid & 1;
  const int dgb = (wid >> 1) * 8;
  const int grp = l >> 4, qn = l & 15;
  const float qxv = sm.s.a.qx[qt * 16 + qn];
  const float qyv = sm.s.a.qy[qt * 16 + qn];
  const float qzv = sm.s.a.qz[qt * 16 + qn];
  const float negm = -sm.s.a.m[qt * 16 + qn];
  const f16x8* BH = wsFh + (size_t)batch * NKT * NDT * 64;
  const f16x8* BL = wsFl + (size_t)batch * NKT * NDT * 64;

  f32x4 acc[8];
#pragma unroll
  for (int j = 0; j < 8; ++j) acc[j] = (f32x4){0.f, 0.f, 0.f, 0.f};
  float ssum = 0.f;
#pragma unroll 1
  for (int kt = 0; kt < NKT; ++kt) {
    f16x8 bh[8], bl[8];
#pragma unroll
    for (int d2 = 0; d2 < 8; ++d2) {
      const size_t fi = ((size_t)kt * NDT + dgb + d2) * 64 + l;
      bh[d2] = BH[fi]; bl[d2] = BL[fi];
    }
    const int pb = kt * 32 + grp * 8;
    float4 av[6];
    {
      const float4* ap = (const float4*)&sm.s.a.ax[pb * 3];
#pragma unroll
      for (int j = 0; j < 6; ++j) av[j] = ap[j];
    }
    const float* af = (const float*)av;
    float w8[8];
#pragma unroll
    for (int j = 0; j < 8; ++j) {
      const float dx = af[3 * j] - qxv, dy = af[3 * j + 1] - qyv, dz = af[3 * j + 2] - qzv;
      const float d = sqrtf(fmaf(dx, dx, fmaf(dy, dy, dz * dz))) + 1e-5f;
      const float u = __expf(fmaf(d * d, -INVVAR, negm));
      w8[j] = u; ssum += u;
    }
    f16x8 ah, al;
    pack_w16(w8, ah, al);
#pragma unroll
    for (int d2 = 0; d2 < 8; ++d2)
      acc[d2] = __builtin_amdgcn_mfma_f32_16x16x32_f16(ah, bh[d2], acc[d2], 0, 0, 0);
#pragma unroll
    for (int d2 = 0; d2 < 8; ++d2)
      acc[d2] = __builtin_amdgcn_mfma_f32_16x16x32_f16(ah, bl[d2], acc[d2], 0, 0, 0);
#pragma unroll
    for (int d2 = 0; d2 < 8; ++d2)
      acc[d2] = __builtin_amdgcn_mfma_f32_16x16x32_f16(al, bh[d2], acc[d2], 0, 0, 0);
  }
  ssum += __shfl_xor(ssum, 16);
  ssum += __shfl_xor(ssum, 32);
  if (wid < 2 && grp == 0) sm.sS[qt * 16 + qn] = ssum;
  __syncthreads();
  float sc[4];
#pragma unroll
  for (int r = 0; r < 4; ++r)
    sc[r] = (1.0f / WSCALE) / sm.sS[qt * 16 + grp * 4 + r];
#pragma unroll
  for (int d2 = 0; d2 < 8; ++d2) {
    const int d = (dgb + d2) * 16 + qn;
    *(float4*)&sm.s.b.u.cT[qsw(d, qt * 16 + grp * 4)] =
        make_float4(acc[d2][0] * sc[0], acc[d2][1] * sc[1],
                    acc[d2][2] * sc[2], acc[d2][3] * sc[3]);
  }
  __syncthreads();

  stage_fc0v(sm.s.b.u.cT, fc0_w, fc0_b, sm.s.b.lat, t);
  __syncthreads();
  stage_h128<DIM, true, false>(sm.s.b.lat, fc1_w, fc1_b, sm.s.b.u.nt.net, t);
  __syncthreads();
#pragma unroll 1
  for (int i = 0; i < NBLK; ++i) {
    stage_h128<DIM, false, true>(sm.s.b.lat, fcc_w + (size_t)i * DIM * HID,
                                 fcc_b + i * HID, sm.s.b.u.nt.net, t);
    __syncthreads();
    stage_h128<HID, true, false>(sm.s.b.u.nt.net, blk_w0 + (size_t)i * HID * HID,
                                 blk_b0 + i * HID, sm.s.b.u.nt.tmp, t);
    __syncthreads();
    stage_h128<HID, true, true>(sm.s.b.u.nt.tmp, blk_w1 + (size_t)i * HID * HID,
                                blk_b1 + i * HID, sm.s.b.u.nt.net, t);
    __syncthreads();
  }
  if (t < TQ * NOUT3) {
    const int q = t / NOUT3, n = t - q * NOUT3;
    float s = out_b[n];
    const float* net = sm.s.b.u.nt.net;
#pragma unroll 8
    for (int k = 0; k < HID; ++k)
      s = fmaf(fmaxf(net[k * TQ + (q ^ (((k >> 2) & 7) << 2))], 0.f),
               out_w[k * NOUT3 + n], s);
    out[((size_t)batch * NQTOT + q0 + q) * NOUT3 + n] = s;
  }
}

extern "C" void kernel_launch(void* const* d_in, const int* in_sizes, int n_in,
                              void* d_out, int out_size, void* d_ws, size_t ws_size,
                              hipStream_t stream) {
  (void)in_sizes; (void)n_in; (void)out_size;
  const float* xyz_q        = (const float*)d_in[0];
  const float* anchors      = (const float*)d_in[1];
  const float* anchor_feats = (const float*)d_in[2];
  const float* fc0_w        = (const float*)d_in[3];
  const float* fc0_b        = (const float*)d_in[4];
  const float* fc1_w        = (const float*)d_in[5];
  const float* fc1_b        = (const float*)d_in[6];
  const float* blk_w0       = (const float*)d_in[7];
  const float* blk_b0       = (const float*)d_in[8];
  const float* blk_w1       = (const float*)d_in[9];
  const float* blk_b1       = (const float*)d_in[10];
  const float* fcc_w        = (const float*)d_in[11];
  const float* fcc_b        = (const float*)d_in[12];
  const float* out_w        = (const float*)d_in[13];
  const float* out_b        = (const float*)d_in[14];
  float* out = (float*)d_out;

  // Layout: FW0 frags (2 x 3.5 MiB) + W frags incl. fc0 (2 x 768 KiB) = 8.91MB
  const size_t F2_BYTES = (size_t)4 * 64 * NDT2 * 64 * 16;      // 3,670,016
  const size_t W2_BYTES = (size_t)NFRAG * 64 * 16;              // 786,432
  if (ws_size >= 2 * F2_BYTES + 2 * W2_BYTES) {
    f16x8* wsFh = (f16x8*)d_ws;
    f16x8* wsFl = (f16x8*)((char*)d_ws + F2_BYTES);
    f16x8* Wh   = (f16x8*)((char*)d_ws + 2 * F2_BYTES);
    f16x8* Wm   = (f16x8*)((char*)d_ws + 2 * F2_BYTES + W2_BYTES);
    hipLaunchKernelGGL(pid_packw, dim3((NFRAG + 3) / 4), dim3(NTHR), 0, stream,
                       fc0_w, fc1_w, fcc_w, blk_w0, blk_w1, Wh, Wm);
    hipLaunchKernelGGL(pid_packfw, dim3(256), dim3(NTHR), 0, stream,
                       anchor_feats, Wh, Wm, (_Float16*)wsFh, (_Float16*)wsFl);
    hipLaunchKernelGGL(pid_fused_mfma, dim3(1024), dim3(NTHR), 0, stream,
                       xyz_q, anchors, wsFh, wsFl, Wh, Wm,
                       fc0_b, fc1_b, blk_b0, blk_b1, fcc_b, out_w, out_b, out);
  } else {
    // V1 fallback: old 16-dt F frags + fp32 vector MLP (needs 8 MiB)
    const size_t F1_BYTES = (size_t)4 * NKT * NDT * 64 * 16;    // 4 MiB
    f16x8* wsFh = (f16x8*)d_ws;
    f16x8* wsFl = (f16x8*)((char*)d_ws + F1_BYTES);
    hipLaunchKernelGGL(pid_packf16, dim3(1024), dim3(NTHR), 0, stream,
                       anchor_feats, wsFh, wsFl);
    hipLaunchKernelGGL(pid_fused_vec, dim3(1024), dim3(NTHR), 0, stream,
                       xyz_q, anchors, wsFh, wsFl,
                       fc0_w, fc0_b, fc1_w, fc1_b, blk_w0, blk_b0,
                       blk_w1, blk_b1, fcc_w, fcc_b, out_w, out_b, out);
  }
}